// Round 4
// baseline (714.116 us; speedup 1.0000x reference)
//
#include <hip/hip_runtime.h>
#include <math.h>

#define NROWS 8192
#define NDET  4096

// ---------------- workspace layout (float element offsets) ----------------
static constexpr int OFF_SGN = 65536;
static constexpr int OFF_PN  = 131072;
static constexpr int OFF_H1  = 1703936;
static constexpr int OFF_H2  = 2228224;
static constexpr int OFF_BAR = 2752512;   // 2 int barrier counters (after h2)

#define TAIL_BLOCKS 512

// ---- fused front-end: blocks [0,512) = pointnet (VALU-bound, starts early),
// blocks [512, 512+8192) = sparse adjacency extraction (HBM-BW-bound, 128 MB scan).
// Block 0 additionally zeroes the tail's grid-barrier counters (replay-safe:
// runs every launch, after the harness workspace poison, before k_tail).
__global__ __launch_bounds__(256) void k_front(
    const float* __restrict__ nodeA, const float* __restrict__ edgeA,
    int* __restrict__ idx, float* __restrict__ sgn,
    const float* __restrict__ x,
    const float* __restrict__ w1, const float* __restrict__ b1,
    const float* __restrict__ g1, const float* __restrict__ be1,
    const float* __restrict__ m1, const float* __restrict__ v1,
    const float* __restrict__ w2, const float* __restrict__ b2,
    const float* __restrict__ g2, const float* __restrict__ be2,
    const float* __restrict__ m2, const float* __restrict__ v2,
    const float* __restrict__ w3, const float* __restrict__ b3,
    const float* __restrict__ g3, const float* __restrict__ be3,
    const float* __restrict__ m3, const float* __restrict__ v3,
    float* __restrict__ pn, int* __restrict__ bar)
{
    __shared__ int   scnt;
    __shared__ float fw[2720];
    int t = threadIdx.x;

    if (blockIdx.x >= 512) {
        // ---------------- extract role ----------------
        int row = blockIdx.x - 512;
        const float* src; int col0;
        if (row < NDET) { src = nodeA + (size_t)row * NROWS + NDET; col0 = NDET; }
        else            { src = edgeA + (size_t)row * NROWS;        col0 = 0;    }
        if (t == 0) scnt = 0;
        __syncthreads();
        const float4* s4 = (const float4*)src;
        #pragma unroll
        for (int it = 0; it < 4; ++it) {
            float4 v = s4[t + it * 256];
            int cb = col0 + (t + it * 256) * 4;
            if (v.x != 0.f) { int p = atomicAdd(&scnt, 1); idx[row * 8 + p] = cb;     sgn[row * 8 + p] = v.x; }
            if (v.y != 0.f) { int p = atomicAdd(&scnt, 1); idx[row * 8 + p] = cb + 1; sgn[row * 8 + p] = v.y; }
            if (v.z != 0.f) { int p = atomicAdd(&scnt, 1); idx[row * 8 + p] = cb + 2; sgn[row * 8 + p] = v.z; }
            if (v.w != 0.f) { int p = atomicAdd(&scnt, 1); idx[row * 8 + p] = cb + 3; sgn[row * 8 + p] = v.w; }
        }
        __syncthreads();
        for (int p = scnt + t; p < 8; p += 256) { idx[row * 8 + p] = 0; sgn[row * 8 + p] = 0.f; }
        return;
    }

    if (blockIdx.x == 0 && t < 2) bar[t] = 0;    // reset tail grid-barrier counters

    // ---------------- pointnet role ----------------
    // folded weights: fw1[3][16]@0, fb1@48, fw2[16][32]@64, fb2@576, fw3[32][64]@608, fb3@2656
    for (int i = t; i < 48; i += 256)  { int d = i & 15; fw[i]       = w1[i] * g1[d] * rsqrtf(v1[d] + 1e-5f); }
    for (int i = t; i < 16; i += 256)  {                 fw[48 + i]  = (b1[i] - m1[i]) * g1[i] * rsqrtf(v1[i] + 1e-5f) + be1[i]; }
    for (int i = t; i < 512; i += 256) { int d = i & 31; fw[64 + i]  = w2[i] * g2[d] * rsqrtf(v2[d] + 1e-5f); }
    for (int i = t; i < 32; i += 256)  {                 fw[576 + i] = (b2[i] - m2[i]) * g2[i] * rsqrtf(v2[i] + 1e-5f) + be2[i]; }
    for (int i = t; i < 2048; i += 256){ int d = i & 63; fw[608 + i] = w3[i] * g3[d] * rsqrtf(v3[d] + 1e-5f); }
    for (int i = t; i < 64; i += 256)  {                 fw[2656 + i]= (b3[i] - m3[i]) * g3[i] * rsqrtf(v3[i] + 1e-5f) + be3[i]; }
    __syncthreads();

    int lane = t & 63;
    int wv   = t >> 6;                               // 4 waves/block
    int l15  = lane & 15, l31 = lane & 31;
    int rowbase = (blockIdx.x * 4 + wv) * 4;         // 512 blocks x 16 rows

    for (int r = rowbase; r < rowbase + 4; ++r) {
        float val  = (lane < 10) ? x[(size_t)r * 74 + 64 + lane] : 0.f;
        float vmax = -3.0e38f;
        #pragma unroll
        for (int p = 0; p < 5; ++p) {
            float a0 = __shfl(val, p, 64);
            float a1 = __shfl(val, p + 5, 64);
            float h1v = fmaxf(0.f, a0 * fw[l15] + a1 * fw[16 + l15] + fw[48 + l15]);
            float s2 = fw[576 + l31];
            #pragma unroll
            for (int d = 0; d < 16; ++d)
                s2 += __shfl(h1v, d, 64) * fw[64 + d * 32 + l31];
            float h2v = fmaxf(0.f, s2);
            float s3 = fw[2656 + lane];
            #pragma unroll
            for (int e = 0; e < 32; ++e)
                s3 += __shfl(h2v, e, 64) * fw[608 + e * 64 + lane];
            vmax = fmaxf(vmax, s3);
        }
        pn[(size_t)r * 64 + lane] = vmax;            // coalesced 256 B/wave
    }
}

// ---- software grid barrier (all TAIL_BLOCKS co-resident by construction) ----
// release: threadfence (drain + L2 writeback) + AGENT-scope RMW
// acquire: AGENT-scope spin load; then every thread fences so post-barrier
// plain loads cannot hit stale L1/L2 lines (incl. lines from a prior replay).
__device__ __forceinline__ void gridbar(int* cnt)
{
    __syncthreads();
    if (threadIdx.x == 0) {
        __threadfence();
        __hip_atomic_fetch_add(cnt, 1, __ATOMIC_RELEASE, __HIP_MEMORY_SCOPE_AGENT);
        while (__hip_atomic_load(cnt, __ATOMIC_ACQUIRE, __HIP_MEMORY_SCOPE_AGENT) < TAIL_BLOCKS)
            __builtin_amdgcn_s_sleep(2);
    }
    __syncthreads();
    __threadfence();
}

// ---- fused tail: fgc1 + fgc2 + gc3 in one dispatch, 2 software grid barriers ----
// 512 blocks x 16 rows; launch_bounds (256,2) caps resources so all 512 blocks
// are co-resident (LDS 17.7KB*2 < 160KB, 256 CUs * 2 = 512). Neighbor tables
// load ONCE and serve all three phases. Per-phase math bit-exact vs split kernels.
__global__ __launch_bounds__(256, 2) void k_tail(
    const float* __restrict__ x, const float* __restrict__ pn,
    const int* __restrict__ idx, const float* __restrict__ sgn,
    const float* __restrict__ g1wn, const float* __restrict__ g1we,
    const float* __restrict__ g1bn, const float* __restrict__ g1be,
    const float* __restrict__ g2wn, const float* __restrict__ g2we,
    const float* __restrict__ g2bn, const float* __restrict__ g2be,
    const float* __restrict__ g3wn, const float* __restrict__ g3we,
    const float* __restrict__ g3bn, const float* __restrict__ g3be,
    float* __restrict__ h1, float* __restrict__ h2, float* __restrict__ out,
    int* bar)
{
    __shared__ float inb[16 * 260];      // fgc1 stride 260; fgc2 reuses with stride 132
    __shared__ int   lidx[128];
    __shared__ float lsgn[128];
    int t = threadIdx.x;
    int r0 = blockIdx.x * 16;
    bool isnode = (blockIdx.x < 256);    // 16-row blocks: boundary at row 4096

    if (t < 128) {
        int ir = t >> 3, j = t & 7;
        lidx[t] = idx[(r0 + ir) * 8 + j];
        lsgn[t] = sgn[(r0 + ir) * 8 + j];
    }
    __syncthreads();

    // ---- phase 1: gather [x|pn] + [own128|agg128] . W1[256][64] -> h1 ----
    {
        int f = t & 127, rrb = t >> 7;   // wave-uniform f<64 / f>=64 split
        #pragma unroll
        for (int pass = 0; pass < 8; ++pass) {
            int rr = rrb + pass * 2;
            int r  = r0 + rr;
            float own = (f < 64) ? x[(size_t)r * 74 + f] : pn[(size_t)r * 64 + (f - 64)];
            float acc = own;
            #pragma unroll
            for (int j = 0; j < 8; ++j) {
                int nb   = lidx[rr * 8 + j];
                float sg = lsgn[rr * 8 + j];
                float v  = (f < 64) ? x[(size_t)nb * 74 + f] : pn[(size_t)nb * 64 + (f - 64)];
                acc += sg * v;
            }
            inb[rr * 260 + f]       = own;
            inb[rr * 260 + 128 + f] = acc;
        }
        __syncthreads();
        int r_l = t >> 4, c0 = (t & 15) * 4;
        const float* W = isnode ? g1wn : g1we;
        const float* B = isnode ? g1bn : g1be;
        float a0 = B[c0], a1 = B[c0 + 1], a2 = B[c0 + 2], a3 = B[c0 + 3];
        #pragma unroll
        for (int kg = 0; kg < 64; ++kg) {
            float4 a = *(const float4*)&inb[r_l * 260 + kg * 4];
            const float* av = &a.x;
            #pragma unroll
            for (int kk = 0; kk < 4; ++kk) {
                float4 w = *(const float4*)&W[(kg * 4 + kk) * 64 + c0];
                a0 += av[kk] * w.x; a1 += av[kk] * w.y;
                a2 += av[kk] * w.z; a3 += av[kk] * w.w;
            }
        }
        float4 o;
        o.x = fmaxf(a0, 0.f); o.y = fmaxf(a1, 0.f);
        o.z = fmaxf(a2, 0.f); o.w = fmaxf(a3, 0.f);
        *(float4*)&h1[(size_t)(r0 + r_l) * 64 + c0] = o;
    }
    gridbar(&bar[0]);
    __syncthreads();   // protect inb reuse (phase 2 rewrites it)

    // ---- phase 2: gather h1 + [own64|agg64] . W2[128][64] -> h2 ----
    {
        int f = t & 63, rrb = t >> 6;
        #pragma unroll
        for (int pass = 0; pass < 4; ++pass) {
            int rr = rrb + pass * 4;
            int r  = r0 + rr;
            float own = h1[(size_t)r * 64 + f];
            float acc = own;
            #pragma unroll
            for (int j = 0; j < 8; ++j) {
                int nb   = lidx[rr * 8 + j];
                float sg = lsgn[rr * 8 + j];
                acc += sg * h1[(size_t)nb * 64 + f];
            }
            inb[rr * 132 + f]      = own;
            inb[rr * 132 + 64 + f] = acc;
        }
        __syncthreads();
        int r_l = t >> 4, c0 = (t & 15) * 4;
        const float* W = isnode ? g2wn : g2we;
        const float* B = isnode ? g2bn : g2be;
        float a0 = B[c0], a1 = B[c0 + 1], a2 = B[c0 + 2], a3 = B[c0 + 3];
        #pragma unroll
        for (int kg = 0; kg < 32; ++kg) {
            float4 a = *(const float4*)&inb[r_l * 132 + kg * 4];
            const float* av = &a.x;
            #pragma unroll
            for (int kk = 0; kk < 4; ++kk) {
                float4 w = *(const float4*)&W[(kg * 4 + kk) * 64 + c0];
                a0 += av[kk] * w.x; a1 += av[kk] * w.y;
                a2 += av[kk] * w.z; a3 += av[kk] * w.w;
            }
        }
        float4 o;
        o.x = fmaxf(a0, 0.f); o.y = fmaxf(a1, 0.f);
        o.z = fmaxf(a2, 0.f); o.w = fmaxf(a3, 0.f);
        *(float4*)&h2[(size_t)(r0 + r_l) * 64 + c0] = o;
    }
    gridbar(&bar[1]);

    // ---- phase 3: gc3 gather + 128->1 dot + sigmoid (wave per row, 4 rows/wave) ----
    {
        int lane = t & 63, wv = t >> 6;
        const float* w = isnode ? g3wn : g3we;
        float bias = isnode ? g3bn[0] : g3be[0];
        for (int rr = wv * 4; rr < wv * 4 + 4; ++rr) {
            int row = r0 + rr;
            float own = h2[(size_t)row * 64 + lane];
            float agg = own;
            #pragma unroll
            for (int j = 0; j < 8; ++j) {
                int nb   = lidx[rr * 8 + j];
                float sg = lsgn[rr * 8 + j];
                agg += sg * h2[(size_t)nb * 64 + lane];
            }
            float acc = own * w[lane] + agg * w[64 + lane];
            #pragma unroll
            for (int off = 32; off > 0; off >>= 1)
                acc += __shfl_xor(acc, off, 64);
            if (lane == 0)
                out[row] = 1.f / (1.f + expf(-(acc + bias)));
        }
    }
}

extern "C" void kernel_launch(void* const* d_in, const int* in_sizes, int n_in,
                              void* d_out, int out_size, void* d_ws, size_t ws_size,
                              hipStream_t stream)
{
    const float* x     = (const float*)d_in[0];
    const float* nodeA = (const float*)d_in[1];
    const float* edgeA = (const float*)d_in[2];
    const float* pw1 = (const float*)d_in[3];  const float* pb1 = (const float*)d_in[4];
    const float* pg1 = (const float*)d_in[5];  const float* pe1 = (const float*)d_in[6];
    const float* pm1 = (const float*)d_in[7];  const float* pv1 = (const float*)d_in[8];
    const float* pw2 = (const float*)d_in[9];  const float* pb2 = (const float*)d_in[10];
    const float* pg2 = (const float*)d_in[11]; const float* pe2 = (const float*)d_in[12];
    const float* pm2 = (const float*)d_in[13]; const float* pv2 = (const float*)d_in[14];
    const float* pw3 = (const float*)d_in[15]; const float* pb3 = (const float*)d_in[16];
    const float* pg3 = (const float*)d_in[17]; const float* pe3 = (const float*)d_in[18];
    const float* pm3 = (const float*)d_in[19]; const float* pv3 = (const float*)d_in[20];
    const float* g1wn = (const float*)d_in[21]; const float* g1we = (const float*)d_in[22];
    const float* g1bn = (const float*)d_in[23]; const float* g1be = (const float*)d_in[24];
    const float* g2wn = (const float*)d_in[25]; const float* g2we = (const float*)d_in[26];
    const float* g2bn = (const float*)d_in[27]; const float* g2be = (const float*)d_in[28];
    const float* g3wn = (const float*)d_in[29]; const float* g3we = (const float*)d_in[30];
    const float* g3bn = (const float*)d_in[31]; const float* g3be = (const float*)d_in[32];

    float* ws  = (float*)d_ws;
    int*   idx = (int*)ws;
    float* sgn = ws + OFF_SGN;
    float* pn  = ws + OFF_PN;
    float* h1  = ws + OFF_H1;
    float* h2  = ws + OFF_H2;
    int*   bar = (int*)(ws + OFF_BAR);
    float* out = (float*)d_out;

    k_front<<<512 + NROWS, 256, 0, stream>>>(nodeA, edgeA, idx, sgn, x,
        pw1, pb1, pg1, pe1, pm1, pv1,
        pw2, pb2, pg2, pe2, pm2, pv2,
        pw3, pb3, pg3, pe3, pm3, pv3, pn, bar);

    k_tail<<<TAIL_BLOCKS, 256, 0, stream>>>(x, pn, idx, sgn,
        g1wn, g1we, g1bn, g1be,
        g2wn, g2we, g2bn, g2be,
        g3wn, g3we, g3bn, g3be,
        h1, h2, out, bar);
}

// Round 5
// 520.616 us; speedup vs baseline: 1.3717x; 1.3717x over previous
//
#include <hip/hip_runtime.h>
#include <math.h>

#define NROWS 8192
#define NDET  4096

// ---------------- workspace layout (float element offsets) ----------------
static constexpr int OFF_SGN = 65536;
static constexpr int OFF_PN  = 131072;
static constexpr int OFF_H1  = 1703936;
static constexpr int OFF_H2  = 2228224;

// ---- fused front-end: blocks [0,512) = pointnet (VALU-bound, starts early),
// blocks [512, 512+8192) = sparse adjacency extraction (HBM-BW-bound, 128 MB scan).
// No data dependency between the two roles; pointnet hides under the extract scan.
// NOTE (R4 lesson): software grid barriers cost ~100us/sync at 512 blocks on this
// chip (cross-XCD spin contention) -- kernel launch boundaries (~6-8us) are the
// cheapest grid-wide sync. Keep the 4-dispatch structure.
__global__ __launch_bounds__(256) void k_front(
    const float* __restrict__ nodeA, const float* __restrict__ edgeA,
    int* __restrict__ idx, float* __restrict__ sgn,
    const float* __restrict__ x,
    const float* __restrict__ w1, const float* __restrict__ b1,
    const float* __restrict__ g1, const float* __restrict__ be1,
    const float* __restrict__ m1, const float* __restrict__ v1,
    const float* __restrict__ w2, const float* __restrict__ b2,
    const float* __restrict__ g2, const float* __restrict__ be2,
    const float* __restrict__ m2, const float* __restrict__ v2,
    const float* __restrict__ w3, const float* __restrict__ b3,
    const float* __restrict__ g3, const float* __restrict__ be3,
    const float* __restrict__ m3, const float* __restrict__ v3,
    float* __restrict__ pn)
{
    __shared__ int   scnt;
    __shared__ float fw[2720];
    int t = threadIdx.x;

    if (blockIdx.x >= 512) {
        // ---------------- extract role ----------------
        int row = blockIdx.x - 512;
        const float* src; int col0;
        if (row < NDET) { src = nodeA + (size_t)row * NROWS + NDET; col0 = NDET; }
        else            { src = edgeA + (size_t)row * NROWS;        col0 = 0;    }
        if (t == 0) scnt = 0;
        __syncthreads();
        const float4* s4 = (const float4*)src;
        #pragma unroll
        for (int it = 0; it < 4; ++it) {
            float4 v = s4[t + it * 256];
            int cb = col0 + (t + it * 256) * 4;
            if (v.x != 0.f) { int p = atomicAdd(&scnt, 1); idx[row * 8 + p] = cb;     sgn[row * 8 + p] = v.x; }
            if (v.y != 0.f) { int p = atomicAdd(&scnt, 1); idx[row * 8 + p] = cb + 1; sgn[row * 8 + p] = v.y; }
            if (v.z != 0.f) { int p = atomicAdd(&scnt, 1); idx[row * 8 + p] = cb + 2; sgn[row * 8 + p] = v.z; }
            if (v.w != 0.f) { int p = atomicAdd(&scnt, 1); idx[row * 8 + p] = cb + 3; sgn[row * 8 + p] = v.w; }
        }
        __syncthreads();
        for (int p = scnt + t; p < 8; p += 256) { idx[row * 8 + p] = 0; sgn[row * 8 + p] = 0.f; }
        return;
    }

    // ---------------- pointnet role ----------------
    // folded weights: fw1[3][16]@0, fb1@48, fw2[16][32]@64, fb2@576, fw3[32][64]@608, fb3@2656
    for (int i = t; i < 48; i += 256)  { int d = i & 15; fw[i]       = w1[i] * g1[d] * rsqrtf(v1[d] + 1e-5f); }
    for (int i = t; i < 16; i += 256)  {                 fw[48 + i]  = (b1[i] - m1[i]) * g1[i] * rsqrtf(v1[i] + 1e-5f) + be1[i]; }
    for (int i = t; i < 512; i += 256) { int d = i & 31; fw[64 + i]  = w2[i] * g2[d] * rsqrtf(v2[d] + 1e-5f); }
    for (int i = t; i < 32; i += 256)  {                 fw[576 + i] = (b2[i] - m2[i]) * g2[i] * rsqrtf(v2[i] + 1e-5f) + be2[i]; }
    for (int i = t; i < 2048; i += 256){ int d = i & 63; fw[608 + i] = w3[i] * g3[d] * rsqrtf(v3[d] + 1e-5f); }
    for (int i = t; i < 64; i += 256)  {                 fw[2656 + i]= (b3[i] - m3[i]) * g3[i] * rsqrtf(v3[i] + 1e-5f) + be3[i]; }
    __syncthreads();

    int lane = t & 63;
    int wv   = t >> 6;                               // 4 waves/block
    int l15  = lane & 15, l31 = lane & 31;
    int rowbase = (blockIdx.x * 4 + wv) * 4;         // 512 blocks x 16 rows

    for (int r = rowbase; r < rowbase + 4; ++r) {
        float val  = (lane < 10) ? x[(size_t)r * 74 + 64 + lane] : 0.f;
        float vmax = -3.0e38f;
        #pragma unroll
        for (int p = 0; p < 5; ++p) {
            float a0 = __shfl(val, p, 64);
            float a1 = __shfl(val, p + 5, 64);
            float h1v = fmaxf(0.f, a0 * fw[l15] + a1 * fw[16 + l15] + fw[48 + l15]);
            float s2 = fw[576 + l31];
            #pragma unroll
            for (int d = 0; d < 16; ++d)
                s2 += __shfl(h1v, d, 64) * fw[64 + d * 32 + l31];
            float h2v = fmaxf(0.f, s2);
            float s3 = fw[2656 + lane];
            #pragma unroll
            for (int e = 0; e < 32; ++e)
                s3 += __shfl(h2v, e, 64) * fw[608 + e * 64 + lane];
            vmax = fmaxf(vmax, s3);
        }
        pn[(size_t)r * 64 + lane] = vmax;            // coalesced 256 B/wave
    }
}

// ---- layer 1 fused: gather (into LDS) + [own128 | agg128] . W[256][64] GEMM ----
// block = 16 rows. Phase A: 2 rows/pass x 8 passes, f = t&127 spans [x64|pn64].
// LDS row stride 260 floats (== 4 mod 32 banks) -> conflict-free b128 broadcast in phase B.
// k-order in phase B matches the reference concat: [own_x | own_pn | agg_x | agg_pn].
__global__ __launch_bounds__(256) void k_fgc1(
    const float* __restrict__ x, const float* __restrict__ pn,
    const int* __restrict__ idx, const float* __restrict__ sgn,
    const float* __restrict__ wn, const float* __restrict__ we,
    const float* __restrict__ bn, const float* __restrict__ be,
    float* __restrict__ out)
{
    __shared__ float inb[16 * 260];
    __shared__ int   lidx[128];
    __shared__ float lsgn[128];
    int t = threadIdx.x;
    int r0 = blockIdx.x * 16;
    if (t < 128) {
        int ir = t >> 3, j = t & 7;
        lidx[t] = idx[(r0 + ir) * 8 + j];
        lsgn[t] = sgn[(r0 + ir) * 8 + j];
    }
    __syncthreads();

    int f   = t & 127;                 // wave-uniform branch: wave0 f<64, wave1 f>=64
    int rrb = t >> 7;
    #pragma unroll
    for (int pass = 0; pass < 8; ++pass) {
        int rr = rrb + pass * 2;
        int r  = r0 + rr;
        float own = (f < 64) ? x[(size_t)r * 74 + f] : pn[(size_t)r * 64 + (f - 64)];
        float acc = own;
        #pragma unroll
        for (int j = 0; j < 8; ++j) {
            int nb   = lidx[rr * 8 + j];
            float sg = lsgn[rr * 8 + j];
            float v  = (f < 64) ? x[(size_t)nb * 74 + f] : pn[(size_t)nb * 64 + (f - 64)];
            acc += sg * v;
        }
        inb[rr * 260 + f]       = own;
        inb[rr * 260 + 128 + f] = acc;
    }
    __syncthreads();

    int r_l = t >> 4, cg = t & 15, c0 = cg * 4;
    bool isnode = (blockIdx.x < 256);   // 16-row blocks: boundary at block 256 == row 4096
    const float* W = isnode ? wn : we;
    const float* B = isnode ? bn : be;
    float a0 = B[c0], a1 = B[c0 + 1], a2 = B[c0 + 2], a3 = B[c0 + 3];
    #pragma unroll
    for (int kg = 0; kg < 64; ++kg) {
        float4 a = *(const float4*)&inb[r_l * 260 + kg * 4];
        const float* av = &a.x;
        #pragma unroll
        for (int kk = 0; kk < 4; ++kk) {
            float4 w = *(const float4*)&W[(kg * 4 + kk) * 64 + c0];
            a0 += av[kk] * w.x; a1 += av[kk] * w.y;
            a2 += av[kk] * w.z; a3 += av[kk] * w.w;
        }
    }
    float4 o;
    o.x = fmaxf(a0, 0.f); o.y = fmaxf(a1, 0.f);
    o.z = fmaxf(a2, 0.f); o.w = fmaxf(a3, 0.f);
    *(float4*)&out[(size_t)(r0 + r_l) * 64 + c0] = o;
}

// ---- layer 2 fused: gather (into LDS) + [own64 | agg64] . W[128][64] GEMM ----
__global__ __launch_bounds__(256) void k_fgc2(
    const float* __restrict__ h, const int* __restrict__ idx,
    const float* __restrict__ sgn,
    const float* __restrict__ wn, const float* __restrict__ we,
    const float* __restrict__ bn, const float* __restrict__ be,
    float* __restrict__ out)
{
    __shared__ float inb[16 * 132];
    __shared__ int   lidx[128];
    __shared__ float lsgn[128];
    int t = threadIdx.x;
    int r0 = blockIdx.x * 16;
    if (t < 128) {
        int ir = t >> 3, j = t & 7;
        lidx[t] = idx[(r0 + ir) * 8 + j];
        lsgn[t] = sgn[(r0 + ir) * 8 + j];
    }
    __syncthreads();

    int f   = t & 63;
    int rrb = t >> 6;                  // 4 rows/pass x 4 passes
    #pragma unroll
    for (int pass = 0; pass < 4; ++pass) {
        int rr = rrb + pass * 4;
        int r  = r0 + rr;
        float own = h[(size_t)r * 64 + f];
        float acc = own;
        #pragma unroll
        for (int j = 0; j < 8; ++j) {
            int nb   = lidx[rr * 8 + j];
            float sg = lsgn[rr * 8 + j];
            acc += sg * h[(size_t)nb * 64 + f];
        }
        inb[rr * 132 + f]      = own;
        inb[rr * 132 + 64 + f] = acc;
    }
    __syncthreads();

    int r_l = t >> 4, cg = t & 15, c0 = cg * 4;
    bool isnode = (blockIdx.x < 256);
    const float* W = isnode ? wn : we;
    const float* B = isnode ? bn : be;
    float a0 = B[c0], a1 = B[c0 + 1], a2 = B[c0 + 2], a3 = B[c0 + 3];
    #pragma unroll
    for (int kg = 0; kg < 32; ++kg) {
        float4 a = *(const float4*)&inb[r_l * 132 + kg * 4];
        const float* av = &a.x;
        #pragma unroll
        for (int kk = 0; kk < 4; ++kk) {
            float4 w = *(const float4*)&W[(kg * 4 + kk) * 64 + c0];
            a0 += av[kk] * w.x; a1 += av[kk] * w.y;
            a2 += av[kk] * w.z; a3 += av[kk] * w.w;
        }
    }
    float4 o;
    o.x = fmaxf(a0, 0.f); o.y = fmaxf(a1, 0.f);
    o.z = fmaxf(a2, 0.f); o.w = fmaxf(a3, 0.f);
    *(float4*)&out[(size_t)(r0 + r_l) * 64 + c0] = o;
}

// ---- layer 3 fused: gather + 128->1 dot + sigmoid, wave per row ----
__global__ __launch_bounds__(256) void k_gc3(
    const float* __restrict__ h2, const int* __restrict__ idx,
    const float* __restrict__ sgn,
    const float* __restrict__ wn, const float* __restrict__ we,
    const float* __restrict__ bn, const float* __restrict__ be,
    float* __restrict__ out)
{
    int lane = threadIdx.x & 63;
    int row  = blockIdx.x * 4 + (threadIdx.x >> 6);
    float own = h2[(size_t)row * 64 + lane];
    float agg = own;
    #pragma unroll
    for (int j = 0; j < 8; ++j) {
        int nb   = idx[row * 8 + j];
        float sg = sgn[row * 8 + j];
        agg += sg * h2[(size_t)nb * 64 + lane];
    }
    bool isnode = row < NDET;                  // wave-uniform (rows per wave aligned)
    const float* w = isnode ? wn : we;
    float bias = isnode ? bn[0] : be[0];
    float acc = own * w[lane] + agg * w[64 + lane];
    #pragma unroll
    for (int off = 32; off > 0; off >>= 1)
        acc += __shfl_xor(acc, off, 64);
    if (lane == 0)
        out[row] = 1.f / (1.f + expf(-(acc + bias)));
}

extern "C" void kernel_launch(void* const* d_in, const int* in_sizes, int n_in,
                              void* d_out, int out_size, void* d_ws, size_t ws_size,
                              hipStream_t stream)
{
    const float* x     = (const float*)d_in[0];
    const float* nodeA = (const float*)d_in[1];
    const float* edgeA = (const float*)d_in[2];
    const float* pw1 = (const float*)d_in[3];  const float* pb1 = (const float*)d_in[4];
    const float* pg1 = (const float*)d_in[5];  const float* pe1 = (const float*)d_in[6];
    const float* pm1 = (const float*)d_in[7];  const float* pv1 = (const float*)d_in[8];
    const float* pw2 = (const float*)d_in[9];  const float* pb2 = (const float*)d_in[10];
    const float* pg2 = (const float*)d_in[11]; const float* pe2 = (const float*)d_in[12];
    const float* pm2 = (const float*)d_in[13]; const float* pv2 = (const float*)d_in[14];
    const float* pw3 = (const float*)d_in[15]; const float* pb3 = (const float*)d_in[16];
    const float* pg3 = (const float*)d_in[17]; const float* pe3 = (const float*)d_in[18];
    const float* pm3 = (const float*)d_in[19]; const float* pv3 = (const float*)d_in[20];
    const float* g1wn = (const float*)d_in[21]; const float* g1we = (const float*)d_in[22];
    const float* g1bn = (const float*)d_in[23]; const float* g1be = (const float*)d_in[24];
    const float* g2wn = (const float*)d_in[25]; const float* g2we = (const float*)d_in[26];
    const float* g2bn = (const float*)d_in[27]; const float* g2be = (const float*)d_in[28];
    const float* g3wn = (const float*)d_in[29]; const float* g3we = (const float*)d_in[30];
    const float* g3bn = (const float*)d_in[31]; const float* g3be = (const float*)d_in[32];

    float* ws  = (float*)d_ws;
    int*   idx = (int*)ws;
    float* sgn = ws + OFF_SGN;
    float* pn  = ws + OFF_PN;
    float* h1  = ws + OFF_H1;
    float* h2  = ws + OFF_H2;
    float* out = (float*)d_out;

    k_front<<<512 + NROWS, 256, 0, stream>>>(nodeA, edgeA, idx, sgn, x,
        pw1, pb1, pg1, pe1, pm1, pv1,
        pw2, pb2, pg2, pe2, pm2, pv2,
        pw3, pb3, pg3, pe3, pm3, pv3, pn);
    k_fgc1<<<512, 256, 0, stream>>>(x, pn, idx, sgn, g1wn, g1we, g1bn, g1be, h1);
    k_fgc2<<<512, 256, 0, stream>>>(h1, idx, sgn, g2wn, g2we, g2bn, g2be, h2);
    k_gc3<<<2048, 256, 0, stream>>>(h2, idx, sgn, g3wn, g3we, g3bn, g3be, out);
}